// Round 1
// baseline (25963.544 us; speedup 1.0000x reference)
//
#include <hip/hip_runtime.h>

#define B_ 64
#define T_ 4096
#define IN_ 128
#define H_ 256
#define TPB 512

static constexpr size_t HBUF_FLOATS = 2ull * B_ * H_;   // [2][B][H]
static constexpr int FLAG_PAD = 32;                      // 128B per flag slot

__device__ __forceinline__ float rdlane_f(float v, int k) {
    return __builtin_bit_cast(float, __builtin_amdgcn_readlane(__builtin_bit_cast(int, v), k));
}

__global__ __launch_bounds__(TPB, 2) void lstm_persist(
    const float* __restrict__ x,      // [B,T,IN]
    const float* __restrict__ W_ih,   // [1024,128]
    const float* __restrict__ W_hh,   // [1024,256]
    const float* __restrict__ b_ih,
    const float* __restrict__ b_hh,
    const float* __restrict__ fc_w,   // [128,256]
    const float* __restrict__ fc_b,   // [128]
    float* __restrict__ out,          // [B,128]
    float* hbuf,                      // [2][B][H]
    unsigned int* flags)              // [2][B][4] padded
{
    const int blk  = blockIdx.x;      // 256 blocks
    const int b    = blk >> 2;
    const int s    = blk & 3;
    const int tid  = threadIdx.x;
    const int lane = tid & 63;
    const int wave = tid >> 6;
    const int half = tid >> 8;                 // 0 (waves 0-3) or 1 (waves 4-7), wave-uniform
    const int r    = (wave & 3) * 64 + lane;   // local gate row 0..255
    const int gt   = r >> 6;                   // gate type 0..3 (i,f,g,o)
    const int j    = r & 63;                   // h-index within slice
    const int grow = gt * 256 + s * 64 + j;    // global gate row 0..1023

    // --- persistent weights in VGPRs ---
    float w_hh[128];
    const float* whh_src = W_hh + (size_t)grow * H_ + half * 128;
    #pragma unroll
    for (int k = 0; k < 128; ++k) w_hh[k] = whh_src[k];
    float w_ih[64];
    const float* wih_src = W_ih + (size_t)grow * IN_ + half * 64;
    #pragma unroll
    for (int k = 0; k < 64; ++k) w_ih[k] = wih_src[k];
    const float bias = (half == 0) ? (b_ih[grow] + b_hh[grow]) : 0.0f;

    __shared__ float g_lds[2][256];   // [half][local row] partial gate sums

    float c_state = 0.0f;             // valid in wave 0 lanes (j = lane)

    const float* xb = x + (size_t)b * T_ * IN_;
    float vx_next = xb[half * 64 + lane];   // prefetch x[t=0]

    for (int t = 0; t < T_; ++t) {
        float acc = bias;
        const float vx = vx_next;
        const int tn = (t + 1 < T_) ? (t + 1) : t;
        vx_next = xb[(size_t)tn * IN_ + half * 64 + lane];   // prefetch next x

        // xp phase (independent of h) — hides under sibling wait
        #pragma unroll
        for (int k = 0; k < 64; ++k)
            acc = fmaf(rdlane_f(vx, k), w_ih[k], acc);

        // wait for h version t in slot (t&1); flags are monotone, >= is safe
        if (tid < 4) {
            unsigned int* fp = flags + (((size_t)(t & 1) * B_ + b) * 4 + tid) * FLAG_PAD;
            while (__hip_atomic_load(fp, __ATOMIC_ACQUIRE, __HIP_MEMORY_SCOPE_AGENT) < (unsigned)t) { }
        }
        __syncthreads();

        // load h_t (fresh: acquire above invalidated L1/L2)
        const float* hsrc = hbuf + ((size_t)(t & 1) * B_ + b) * H_;
        const float vh_a = hsrc[half * 128 + lane];
        const float vh_b = hsrc[half * 128 + 64 + lane];

        // recurrent matvec: readlane-broadcast h into SGPR operand of v_fmac
        #pragma unroll
        for (int k = 0; k < 64; ++k)
            acc = fmaf(rdlane_f(vh_a, k), w_hh[k], acc);
        #pragma unroll
        for (int k = 0; k < 64; ++k)
            acc = fmaf(rdlane_f(vh_b, k), w_hh[64 + k], acc);

        g_lds[half][r] = acc;
        __syncthreads();

        // LSTM cell update: wave 0, lane = j
        if (tid < 64) {
            const float gi = g_lds[0][lane]       + g_lds[1][lane];
            const float gf = g_lds[0][64 + lane]  + g_lds[1][64 + lane];
            const float gg = g_lds[0][128 + lane] + g_lds[1][128 + lane];
            const float go = g_lds[0][192 + lane] + g_lds[1][192 + lane];
            const float i_ = 1.0f / (1.0f + __expf(-gi));
            const float f_ = 1.0f / (1.0f + __expf(-gf));
            const float g_ = tanhf(gg);
            const float o_ = 1.0f / (1.0f + __expf(-go));
            c_state = f_ * c_state + i_ * g_;
            const float h_ = o_ * tanhf(c_state);
            hbuf[((size_t)((t + 1) & 1) * B_ + b) * H_ + s * 64 + lane] = h_;
        }
        if (tid == 0) {
            unsigned int* fp = flags + (((size_t)((t + 1) & 1) * B_ + b) * 4 + s) * FLAG_PAD;
            __hip_atomic_store(fp, (unsigned)(t + 1), __ATOMIC_RELEASE, __HIP_MEMORY_SCOPE_AGENT);
        }
        __syncthreads();   // protects g_lds reuse next iteration
    }

    // ---- final FC: out[b, 32s .. 32s+32) ----
    if (tid < 4) {
        unsigned int* fp = flags + (((size_t)(T_ & 1) * B_ + b) * 4 + tid) * FLAG_PAD;
        while (__hip_atomic_load(fp, __ATOMIC_ACQUIRE, __HIP_MEMORY_SCOPE_AGENT) < (unsigned)T_) { }
    }
    __syncthreads();
    const float* hT = hbuf + ((size_t)(T_ & 1) * B_ + b) * H_;
    const int c = s * 32 + (tid >> 4);   // output channel
    const int q = tid & 15;
    float p = 0.0f;
    #pragma unroll
    for (int e = 0; e < 16; ++e)
        p = fmaf(fc_w[(size_t)c * H_ + q * 16 + e], hT[q * 16 + e], p);
    p += __shfl_xor(p, 1);
    p += __shfl_xor(p, 2);
    p += __shfl_xor(p, 4);
    p += __shfl_xor(p, 8);
    if (q == 0) out[(size_t)b * 128 + c] = p + fc_b[c];
}

extern "C" void kernel_launch(void* const* d_in, const int* in_sizes, int n_in,
                              void* d_out, int out_size, void* d_ws, size_t ws_size,
                              hipStream_t stream) {
    const float* x    = (const float*)d_in[0];
    const float* W_ih = (const float*)d_in[1];
    const float* W_hh = (const float*)d_in[2];
    const float* b_ih = (const float*)d_in[3];
    const float* b_hh = (const float*)d_in[4];
    const float* fc_w = (const float*)d_in[5];
    const float* fc_b = (const float*)d_in[6];
    float* out = (float*)d_out;

    float* hbuf = (float*)d_ws;
    unsigned int* flags = (unsigned int*)((char*)d_ws + HBUF_FLOATS * sizeof(float));
    const size_t clear_bytes = HBUF_FLOATS * sizeof(float)
                             + 2ull * B_ * 4 * FLAG_PAD * sizeof(unsigned int);
    hipMemsetAsync(d_ws, 0, clear_bytes, stream);

    lstm_persist<<<B_ * 4, TPB, 0, stream>>>(x, W_ih, W_hh, b_ih, b_hh, fc_w, fc_b,
                                             out, hbuf, flags);
}

// Round 2
// 8285.443 us; speedup vs baseline: 3.1336x; 3.1336x over previous
//
#include <hip/hip_runtime.h>

#define B_ 64
#define T_ 4096
#define IN_ 128
#define H_ 256
#define TPB 512

using u64 = unsigned long long;

static constexpr size_t HB2_BYTES = 2ull * B_ * H_ * sizeof(u64);   // 256 KiB

__device__ __forceinline__ float rdlane_f(float v, int k) {
    return __builtin_bit_cast(float, __builtin_amdgcn_readlane(__builtin_bit_cast(int, v), k));
}
__device__ __forceinline__ float fast_rcp(float x) { return __builtin_amdgcn_rcpf(x); }
__device__ __forceinline__ float fast_sigmoid(float x) {
    return fast_rcp(1.0f + __expf(-x));
}
__device__ __forceinline__ float fast_tanh(float x) {
    float ax = fabsf(x);
    float e  = __expf(-2.0f * ax);               // in (0,1], no overflow
    float t  = (1.0f - e) * fast_rcp(1.0f + e);
    return copysignf(t, x);
}
__device__ __forceinline__ u64 ld_agent(const u64* p) {
    return __hip_atomic_load(p, __ATOMIC_RELAXED, __HIP_MEMORY_SCOPE_AGENT);
}

__global__ __launch_bounds__(TPB, 1) void lstm_persist(
    const float* __restrict__ x,      // [B,T,IN]
    const float* __restrict__ W_ih,   // [1024,128]
    const float* __restrict__ W_hh,   // [1024,256]
    const float* __restrict__ b_ih,
    const float* __restrict__ b_hh,
    const float* __restrict__ fc_w,   // [128,256]
    const float* __restrict__ fc_b,   // [128]
    float* __restrict__ out,          // [B,128]
    u64* hb2)                         // [2][B][H] packed {ver<<32 | f32(h)}
{
    const int blk  = blockIdx.x;      // 256 blocks
    // XCD-colocate the 4 slices of a batch: xcd = blk & 7 (HW round-robin)
    const int xcd  = blk & 7;
    const int m    = blk >> 3;
    const int s    = m & 3;                    // h-slice 0..3
    const int b    = ((m >> 2) << 3) | xcd;    // batch 0..63
    const int tid  = threadIdx.x;
    const int lane = tid & 63;
    const int wave = tid >> 6;
    const int half = tid >> 8;                 // K-half: waves 0-3 -> 0, 4-7 -> 1
    const int r    = (wave & 3) * 64 + lane;   // local gate row 0..255
    const int gt   = r >> 6;                   // gate type (i,f,g,o)
    const int j    = r & 63;
    const int grow = gt * 256 + s * 64 + j;    // global gate row 0..1023

    // --- persistent weights in VGPRs (192 regs/thread) ---
    float w_hh[128];
    const float* whh_src = W_hh + (size_t)grow * H_ + half * 128;
    #pragma unroll
    for (int k = 0; k < 128; ++k) w_hh[k] = whh_src[k];
    float w_ih[64];
    const float* wih_src = W_ih + (size_t)grow * IN_ + half * 64;
    #pragma unroll
    for (int k = 0; k < 64; ++k) w_ih[k] = wih_src[k];
    const float bias = (half == 0) ? (b_ih[grow] + b_hh[grow]) : 0.0f;

    __shared__ float g_lds[2][256];   // [half][local row] partial gate sums

    float c_state = 0.0f;             // valid in wave 0 (j = lane)

    const float* xb = x + (size_t)b * T_ * IN_;
    float vx_next = xb[half * 64 + lane];      // prefetch x[t=0]

    u64* const slice_out = hb2 /* slot added per-step */ + (size_t)b * H_ + s * 64 + lane;

    for (int t = 0; t < T_; ++t) {
        const u64* pa = hb2 + ((size_t)(t & 1) * B_ + b) * H_ + (half * 128 + lane);
        const u64* pb = pa + 64;
        // issue sync loads first so their latency hides under the xp FMAs
        u64 va = ld_agent(pa);
        u64 vb = ld_agent(pb);

        float acc = bias;
        const float vx = vx_next;
        const int tn = (t + 1 < T_) ? (t + 1) : t;
        vx_next = xb[(size_t)tn * IN_ + half * 64 + lane];

        #pragma unroll
        for (int k = 0; k < 64; ++k)
            acc = fmaf(rdlane_f(vx, k), w_ih[k], acc);

        // data-is-flag spin: version >= t means h_t is present (monotone)
        const unsigned tv = (unsigned)t;
        while ((unsigned)(va >> 32) < tv || (unsigned)(vb >> 32) < tv) {
            va = ld_agent(pa);
            vb = ld_agent(pb);
        }
        const float vh_a = __builtin_bit_cast(float, (unsigned)va);
        const float vh_b = __builtin_bit_cast(float, (unsigned)vb);

        #pragma unroll
        for (int k = 0; k < 64; ++k)
            acc = fmaf(rdlane_f(vh_a, k), w_hh[k], acc);
        #pragma unroll
        for (int k = 0; k < 64; ++k)
            acc = fmaf(rdlane_f(vh_b, k), w_hh[64 + k], acc);

        g_lds[half][r] = acc;
        __syncthreads();

        if (tid < 64) {
            const float gi = g_lds[0][lane]       + g_lds[1][lane];
            const float gf = g_lds[0][64 + lane]  + g_lds[1][64 + lane];
            const float gg = g_lds[0][128 + lane] + g_lds[1][128 + lane];
            const float go = g_lds[0][192 + lane] + g_lds[1][192 + lane];
            const float i_ = fast_sigmoid(gi);
            const float f_ = fast_sigmoid(gf);
            const float g_ = fast_tanh(gg);
            const float o_ = fast_sigmoid(go);
            c_state = fmaf(f_, c_state, i_ * g_);
            const float h_ = o_ * fast_tanh(c_state);
            const u64 pk = ((u64)(unsigned)(t + 1) << 32)
                         | (u64)__builtin_bit_cast(unsigned, h_);
            __hip_atomic_store(slice_out + (size_t)((t + 1) & 1) * B_ * H_, pk,
                               __ATOMIC_RELAXED, __HIP_MEMORY_SCOPE_AGENT);
        }
        __syncthreads();   // g_lds reuse next iteration
    }

    // ---- final FC: out[b, 32s .. 32s+32) ----
    const u64* hT = hb2 + ((size_t)(T_ & 1) * B_ + b) * H_;
    const int c = s * 32 + (tid >> 4);   // output channel
    const int q = tid & 15;
    float p = 0.0f;
    #pragma unroll
    for (int e = 0; e < 16; ++e) {
        u64 v;
        do { v = ld_agent(hT + q * 16 + e); } while ((unsigned)(v >> 32) < (unsigned)T_);
        p = fmaf(fc_w[(size_t)c * H_ + q * 16 + e],
                 __builtin_bit_cast(float, (unsigned)v), p);
    }
    p += __shfl_xor(p, 1);
    p += __shfl_xor(p, 2);
    p += __shfl_xor(p, 4);
    p += __shfl_xor(p, 8);
    if (q == 0) out[(size_t)b * 128 + c] = p + fc_b[c];
}

extern "C" void kernel_launch(void* const* d_in, const int* in_sizes, int n_in,
                              void* d_out, int out_size, void* d_ws, size_t ws_size,
                              hipStream_t stream) {
    const float* x    = (const float*)d_in[0];
    const float* W_ih = (const float*)d_in[1];
    const float* W_hh = (const float*)d_in[2];
    const float* b_ih = (const float*)d_in[3];
    const float* b_hh = (const float*)d_in[4];
    const float* fc_w = (const float*)d_in[5];
    const float* fc_b = (const float*)d_in[6];
    float* out = (float*)d_out;

    u64* hb2 = (u64*)d_ws;
    // {ver=0, h=0.0f} everywhere == the correct initial state
    hipMemsetAsync(d_ws, 0, HB2_BYTES, stream);

    lstm_persist<<<B_ * 4, TPB, 0, stream>>>(x, W_ih, W_hh, b_ih, b_hh, fc_w, fc_b,
                                             out, hb2);
}

// Round 3
// 6006.689 us; speedup vs baseline: 4.3224x; 1.3794x over previous
//
#include <hip/hip_runtime.h>

#define B_ 64
#define T_ 4096
#define IN_ 128
#define H_ 256
#define TPB 512

using u64 = unsigned long long;

static constexpr size_t HB2_BYTES = 2ull * B_ * H_ * sizeof(u64);   // 256 KiB

__device__ __forceinline__ float rdlane_f(float v, int k) {
    return __builtin_bit_cast(float, __builtin_amdgcn_readlane(__builtin_bit_cast(int, v), k));
}
__device__ __forceinline__ float fast_rcp(float x) { return __builtin_amdgcn_rcpf(x); }
__device__ __forceinline__ float fast_sigmoid(float x) {
    return fast_rcp(1.0f + __expf(-x));
}
__device__ __forceinline__ float fast_tanh(float x) {
    float ax = fabsf(x);
    float e  = __expf(-2.0f * ax);
    float t  = (1.0f - e) * fast_rcp(1.0f + e);
    return copysignf(t, x);
}
__device__ __forceinline__ u64 ld_agent(const u64* p) {
    return __hip_atomic_load(p, __ATOMIC_RELAXED, __HIP_MEMORY_SCOPE_AGENT);
}
__device__ __forceinline__ void st_agent(u64* p, u64 v) {
    __hip_atomic_store(p, v, __ATOMIC_RELAXED, __HIP_MEMORY_SCOPE_AGENT);
}

__global__ __launch_bounds__(TPB, 2) void lstm_persist(
    const float* __restrict__ x,      // [B,T,IN]
    const float* __restrict__ W_ih,   // [1024,128]
    const float* __restrict__ W_hh,   // [1024,256]
    const float* __restrict__ b_ih,
    const float* __restrict__ b_hh,
    const float* __restrict__ fc_w,   // [128,256]
    const float* __restrict__ fc_b,   // [128]
    float* __restrict__ out,          // [B,128]
    u64* hb2)                         // [2][B][256] packed {ver<<32 | f32(h)}
{
    const int blk  = blockIdx.x;               // 256 blocks
    const int xcd  = blk & 7;                  // colocate a batch's 4 slices per XCD
    const int m    = blk >> 3;
    const int s    = m & 3;                    // h-slice this block PRODUCES
    const int b    = ((m >> 2) << 3) | xcd;    // batch
    const int tid  = threadIdx.x;
    const int lane = tid & 63;
    const int wave = tid >> 6;
    const int chunk = wave & 3;                // h-chunk this wave CONSUMES (SIMD = wave&3)
    const int sub   = wave >> 2;               // 32-wide K sub-chunk
    const bool is_upd = (wave == s);           // producer wave: h-chunk s in registers

    // lane l accumulates gates {i,f,g,o} for h-index (s*64 + l), K-chunk [k_hh, k_hh+32)
    const int row_base = s * 64 + lane;
    const int k_hh = chunk * 64 + sub * 32;
    const int k_ih = chunk * 32 + sub * 16;

    // --- persistent weights: 4 rows x 32 K (hh) + 4 rows x 16 K (ih) = 192 regs ---
    float w_hh[4][32];
    #pragma unroll
    for (int g = 0; g < 4; ++g) {
        const float4* src = (const float4*)(W_hh + (size_t)(g * 256 + row_base) * H_ + k_hh);
        #pragma unroll
        for (int q = 0; q < 8; ++q) {
            const float4 v = src[q];
            w_hh[g][q*4+0] = v.x; w_hh[g][q*4+1] = v.y;
            w_hh[g][q*4+2] = v.z; w_hh[g][q*4+3] = v.w;
        }
    }
    float w_ih[4][16];
    #pragma unroll
    for (int g = 0; g < 4; ++g) {
        const float4* src = (const float4*)(W_ih + (size_t)(g * 256 + row_base) * IN_ + k_ih);
        #pragma unroll
        for (int q = 0; q < 4; ++q) {
            const float4 v = src[q];
            w_ih[g][q*4+0] = v.x; w_ih[g][q*4+1] = v.y;
            w_ih[g][q*4+2] = v.z; w_ih[g][q*4+3] = v.w;
        }
    }
    float bias_[4] = {0.f, 0.f, 0.f, 0.f};
    if (is_upd) {
        #pragma unroll
        for (int g = 0; g < 4; ++g)
            bias_[g] = b_ih[g * 256 + row_base] + b_hh[g * 256 + row_base];
    }

    __shared__ float part[2][8][4][64];   // [parity][wave][gate][h-idx] — conflict-free

    float h_own = 0.0f, c_own = 0.0f;     // producer wave state (lane l <-> h[s*64+l])

    const float* xb = x + (size_t)b * T_ * IN_;
    float vx = xb[k_ih + (lane & 15)];    // x[t=0], lanes 0..15 hold the 16 needed values

    u64* const hb_b = hb2 + (size_t)b * 256;                       // + parity*B_*256
    const u64* const poll0 = hb2 + (size_t)b * 256 + chunk * 64 + lane;

    for (int t = 0; t < T_; ++t) {
        const int p  = t & 1;
        const int pn = p ^ 1;
        float a0 = 0.f, a1 = 0.f, a2 = 0.f, a3 = 0.f;

        const int tn = (t + 1 < T_) ? t + 1 : t;
        const float vxn = xb[(size_t)tn * IN_ + k_ih + (lane & 15)];   // prefetch

        // ih contribution — independent of h, hides under producer update + hop
        #pragma unroll
        for (int k = 0; k < 16; ++k) {
            const float xv = rdlane_f(vx, k);
            a0 = fmaf(xv, w_ih[0][k], a0);
            a1 = fmaf(xv, w_ih[1][k], a1);
            a2 = fmaf(xv, w_ih[2][k], a2);
            a3 = fmaf(xv, w_ih[3][k], a3);
        }
        vx = vxn;

        // obtain this wave's h-chunk (64 values across lanes)
        float vh;
        if (is_upd) {
            vh = h_own;                   // register fast path
        } else {
            const u64* pp = poll0 + (size_t)p * (B_ * 256);
            u64 v = ld_agent(pp);
            const unsigned tv = (unsigned)t;
            while ((unsigned)(v >> 32) < tv) v = ld_agent(pp);   // data-is-flag
            vh = __builtin_bit_cast(float, (unsigned)v);
        }

        // hh FMAs: 1 readlane + 4 fmac per k (4 independent acc chains)
        if (sub == 0) {
            #pragma unroll
            for (int k = 0; k < 32; ++k) {
                const float hv = rdlane_f(vh, k);
                a0 = fmaf(hv, w_hh[0][k], a0);
                a1 = fmaf(hv, w_hh[1][k], a1);
                a2 = fmaf(hv, w_hh[2][k], a2);
                a3 = fmaf(hv, w_hh[3][k], a3);
            }
        } else {
            #pragma unroll
            for (int k = 0; k < 32; ++k) {
                const float hv = rdlane_f(vh, 32 + k);
                a0 = fmaf(hv, w_hh[0][k], a0);
                a1 = fmaf(hv, w_hh[1][k], a1);
                a2 = fmaf(hv, w_hh[2][k], a2);
                a3 = fmaf(hv, w_hh[3][k], a3);
            }
        }

        part[p][wave][0][lane] = a0;
        part[p][wave][1][lane] = a1;
        part[p][wave][2][lane] = a2;
        part[p][wave][3][lane] = a3;
        __syncthreads();

        if (is_upd) {
            float gi = bias_[0], gf = bias_[1], gg = bias_[2], go = bias_[3];
            #pragma unroll
            for (int pc = 0; pc < 8; ++pc) {
                gi += part[p][pc][0][lane];
                gf += part[p][pc][1][lane];
                gg += part[p][pc][2][lane];
                go += part[p][pc][3][lane];
            }
            const float i_ = fast_sigmoid(gi);
            const float f_ = fast_sigmoid(gf);
            const float g_ = fast_tanh(gg);
            const float o_ = fast_sigmoid(go);
            c_own = fmaf(f_, c_own, i_ * g_);
            h_own = o_ * fast_tanh(c_own);
            const u64 pk = ((u64)(unsigned)(t + 1) << 32)
                         | (u64)__builtin_bit_cast(unsigned, h_own);
            st_agent(hb_b + (size_t)pn * (B_ * 256) + s * 64 + lane, pk);
        }
        // partial buffer is parity-double-buffered: no second barrier needed
    }

    // ---- final FC: out[b, 32s .. 32s+32) ----
    const u64* hT = hb2 + (size_t)(T_ & 1) * (B_ * 256) + (size_t)b * 256;
    const int c = s * 32 + (tid >> 4);
    const int q = tid & 15;
    float pacc = 0.0f;
    #pragma unroll
    for (int e = 0; e < 16; ++e) {
        u64 v;
        do { v = ld_agent(hT + q * 16 + e); } while ((unsigned)(v >> 32) < (unsigned)T_);
        pacc = fmaf(fc_w[(size_t)c * H_ + q * 16 + e],
                    __builtin_bit_cast(float, (unsigned)v), pacc);
    }
    pacc += __shfl_xor(pacc, 1);
    pacc += __shfl_xor(pacc, 2);
    pacc += __shfl_xor(pacc, 4);
    pacc += __shfl_xor(pacc, 8);
    if (q == 0) out[(size_t)b * 128 + c] = pacc + fc_b[c];
}

extern "C" void kernel_launch(void* const* d_in, const int* in_sizes, int n_in,
                              void* d_out, int out_size, void* d_ws, size_t ws_size,
                              hipStream_t stream) {
    const float* x    = (const float*)d_in[0];
    const float* W_ih = (const float*)d_in[1];
    const float* W_hh = (const float*)d_in[2];
    const float* b_ih = (const float*)d_in[3];
    const float* b_hh = (const float*)d_in[4];
    const float* fc_w = (const float*)d_in[5];
    const float* fc_b = (const float*)d_in[6];
    float* out = (float*)d_out;

    u64* hb2 = (u64*)d_ws;
    // {ver=0, h=0.0f} everywhere == the correct initial state
    hipMemsetAsync(d_ws, 0, HB2_BYTES, stream);

    lstm_persist<<<B_ * 4, TPB, 0, stream>>>(x, W_ih, W_hh, b_ih, b_hh, fc_w, fc_b,
                                             out, hb2);
}